// Round 3
// baseline (912.859 us; speedup 1.0000x reference)
//
#include <hip/hip_runtime.h>
#include <hip/hip_bf16.h>

// out[m,n] = sum_r sum_k inp[r,m,k] * wgt[r,n,k]
// W=8, M=N=4096, K=1792 -> single GEMM M=N=4096, Ktot=14336, fp32 in/out,
// bf16 MFMA (absmax 7.8e-3 vs 3.39e-2 threshold).
//
// FUSED: no separate convert pass. The GEMM reg-stages f32 from global,
// converts to bf16 with v_cvt_pk_bf16_f32 (RNE), and ds_writes into the
// same swizzled LDS layout the verified R0 kernel used. Depth-2 counted
// vmcnt(8) pipeline (never drained to 0 in the main loop).

#define Wsz 8
#define Mdim 4096
#define Ndim 4096
#define Kshard 1792
#define KTOT 14336
#define LDSBUF 32768   // one stage: A 16KB + B 16KB (bf16)
#define MK ((size_t)Mdim * Kshard)

typedef __attribute__((ext_vector_type(8))) short short8;
typedef __attribute__((ext_vector_type(4))) float f32x4;

struct Stage { float4 a0l, a0h, a1l, a1h, b0l, b0h, b1l, b1h; };

// ---------------------------------------------------------------------------
// 256x256 tile GEMM, BK=32 (bf16 K-units), 512 threads (8 waves as 4Mx2N).
// K-step s covers bf16 k in [s*32, s*32+32); shard r = s/56, kk = (s%56)*32
// (Kshard % 32 == 0, so a step never straddles a shard boundary).
// ---------------------------------------------------------------------------
__global__ void __launch_bounds__(512, 2) gemm_fused(const float* __restrict__ A,
                                                     const float* __restrict__ B,
                                                     float* __restrict__ C) {
    extern __shared__ char smem[];   // 2 * LDSBUF = 64 KiB

    const int tid = threadIdx.x;
    const int w = tid >> 6, lane = tid & 63;
    const int l15 = lane & 15, quad = lane >> 4;
    const int wm = (w >> 1) * 64;    // wave M offset (0..192)
    const int wn = (w & 1) * 128;    // wave N offset (0/128)

    // XCD-chunked swizzle: 256 wgs, 8 XCDs, 32 wgs/XCD = 2 full M-rows of 16
    // N-tiles -> same-row blocks co-resident on one XCD share per-step
    // A-slices in that XCD's L2.
    const int wgid = (blockIdx.x & 7) * 32 + (blockIdx.x >> 3);
    const long bm = (long)(wgid >> 4) * 256, bn = (long)(wgid & 15) * 256;

    // --- staging decode (identical math to the verified kernel):
    // chunk g covers LDS bytes [g*16, g*16+16) of a 128-row half-tile;
    // row sr = g>>2, dst col c = g&3, GLOBAL k-chunk sq = c ^ ((sr>>1)&3)
    // -> fragment reads see 0 bank conflicts (measured R0).
    const int g = w * 64 + lane;              // 0..511
    const int sr = g >> 2;                    // 0..127
    const int sq = (g & 3) ^ ((sr >> 1) & 3);
    const float* aRow0 = A + (size_t)(bm + sr) * Kshard + sq * 8;
    const float* aRow1 = aRow0 + (size_t)128 * Kshard;
    const float* bRow0 = B + (size_t)(bn + sr) * Kshard + sq * 8;
    const float* bRow1 = bRow0 + (size_t)128 * Kshard;
    const int ldsWr = g * 16;                 // linear chunk byte offset

    // --- fragment read offsets (row stride 64B, swizzled 16B column)
    const int swz = (quad ^ ((l15 >> 1) & 3)) * 16;
    const int aoff = (wm + l15) * 64 + swz;
    const int boff = 16384 + (wn + l15) * 64 + swz;

    f32x4 acc[4][8] = {};

#define ISSUE(S, off)                                           \
    do {                                                        \
        S.a0l = *(const float4*)(aRow0 + (off));                \
        S.a0h = *(const float4*)(aRow0 + (off) + 4);            \
        S.a1l = *(const float4*)(aRow1 + (off));                \
        S.a1h = *(const float4*)(aRow1 + (off) + 4);            \
        S.b0l = *(const float4*)(bRow0 + (off));                \
        S.b0h = *(const float4*)(bRow0 + (off) + 4);            \
        S.b1l = *(const float4*)(bRow1 + (off));                \
        S.b1h = *(const float4*)(bRow1 + (off) + 4);            \
    } while (0)

    // pack 8 f32 -> 8 bf16 (RNE) : element k lands in bits[16k:16k+15]
#define CV4(dst, lo, hi)                                                          \
    do {                                                                          \
        asm("v_cvt_pk_bf16_f32 %0, %1, %2" : "=v"(dst.x) : "v"(lo.x), "v"(lo.y)); \
        asm("v_cvt_pk_bf16_f32 %0, %1, %2" : "=v"(dst.y) : "v"(lo.z), "v"(lo.w)); \
        asm("v_cvt_pk_bf16_f32 %0, %1, %2" : "=v"(dst.z) : "v"(hi.x), "v"(hi.y)); \
        asm("v_cvt_pk_bf16_f32 %0, %1, %2" : "=v"(dst.w) : "v"(hi.z), "v"(hi.w)); \
    } while (0)

#define CONVWRITE(S, base)                                      \
    do {                                                        \
        uint4 oA0, oA1, oB0, oB1;                               \
        CV4(oA0, S.a0l, S.a0h);                                 \
        CV4(oA1, S.a1l, S.a1h);                                 \
        CV4(oB0, S.b0l, S.b0h);                                 \
        CV4(oB1, S.b1l, S.b1h);                                 \
        *(uint4*)(smem + (base) + ldsWr) = oA0;                 \
        *(uint4*)(smem + (base) + 8192 + ldsWr) = oA1;          \
        *(uint4*)(smem + (base) + 16384 + ldsWr) = oB0;         \
        *(uint4*)(smem + (base) + 24576 + ldsWr) = oB1;         \
    } while (0)

    // single-region K-step compute (R0-verified): compiler interleaves
    // 12 ds_read_b128 with 32 MFMA using fine-grained lgkmcnt.
#define COMPUTE(bufbase)                                                                 \
    do {                                                                                 \
        short8 af[4], bfr[8];                                                            \
        _Pragma("unroll") for (int i = 0; i < 4; ++i)                                    \
            af[i] = *(const short8*)(smem + (bufbase) + aoff + i * 1024);                \
        _Pragma("unroll") for (int i = 0; i < 8; ++i)                                    \
            bfr[i] = *(const short8*)(smem + (bufbase) + boff + i * 1024);               \
        _Pragma("unroll") for (int mi = 0; mi < 4; ++mi)                                 \
            _Pragma("unroll") for (int ni = 0; ni < 8; ++ni)                             \
                acc[mi][ni] = __builtin_amdgcn_mfma_f32_16x16x32_bf16(af[mi], bfr[ni],   \
                                                                      acc[mi][ni], 0, 0, 0); \
    } while (0)

#define ADV() do { kkI += 32; if (kkI == Kshard) { kkI = 0; baseI += MK; } } while (0)
#define SB() __builtin_amdgcn_sched_barrier(0)
#define WAIT_VM8() asm volatile("s_waitcnt vmcnt(8)" ::: "memory")
#define WAIT_VM0() asm volatile("s_waitcnt vmcnt(0)" ::: "memory")
#define ENDSTEP()  asm volatile("s_waitcnt lgkmcnt(0)\ns_barrier" ::: "memory")

    Stage S0, S1;
    size_t baseI = 0;
    int kkI = 32;                      // kk of the last-issued step (step 1)

    // prologue: issue G(0)->S0, G(1)->S1; convert G(0) into buf0.
    ISSUE(S0, 0);
    ISSUE(S1, 32);
    WAIT_VM8(); SB();
    CONVWRITE(S0, 0);
    ENDSTEP(); SB();

    // steady: 448 steps total; loop covers steps 0..443 (222 x unroll-2).
    // step t: issue G(t+2), compute buf[t&1], wait older 8 loads (G(t+1)),
    // convert into buf[(t+1)&1], lgkmcnt(0)+barrier. vmcnt never hits 0.
    for (int blk = 0; blk < 222; ++blk) {
        // even step
        ADV(); ISSUE(S0, baseI + kkI); SB();
        COMPUTE(0);
        WAIT_VM8(); SB();
        CONVWRITE(S1, LDSBUF);
        ENDSTEP(); SB();
        // odd step
        ADV(); ISSUE(S1, baseI + kkI); SB();
        COMPUTE(LDSBUF);
        WAIT_VM8(); SB();
        CONVWRITE(S0, 0);
        ENDSTEP(); SB();
    }

    // tail: steps 444..447
    ADV(); ISSUE(S0, baseI + kkI); SB();      // G(446)
    COMPUTE(0);
    WAIT_VM8(); SB();
    CONVWRITE(S1, LDSBUF);
    ENDSTEP(); SB();

    ADV(); ISSUE(S1, baseI + kkI); SB();      // G(447)
    COMPUTE(LDSBUF);
    WAIT_VM8(); SB();
    CONVWRITE(S0, 0);
    ENDSTEP(); SB();

    COMPUTE(0);                                // step 446
    WAIT_VM0(); SB();
    CONVWRITE(S1, LDSBUF);
    ENDSTEP(); SB();

    COMPUTE(LDSBUF);                           // step 447

#undef ISSUE
#undef CV4
#undef CONVWRITE
#undef COMPUTE
#undef ADV
#undef SB
#undef WAIT_VM8
#undef WAIT_VM0
#undef ENDSTEP

    // C/D layout (m89/m91): col = lane&15, row = quad*4 + reg
#pragma unroll
    for (int mi = 0; mi < 4; ++mi)
#pragma unroll
        for (int ni = 0; ni < 8; ++ni) {
            const long col = bn + wn + ni * 16 + l15;
#pragma unroll
            for (int r2 = 0; r2 < 4; ++r2) {
                const long row = bm + wm + mi * 16 + quad * 4 + r2;
                C[row * Ndim + col] = acc[mi][ni][r2];
            }
        }
}

extern "C" void kernel_launch(void* const* d_in, const int* in_sizes, int n_in,
                              void* d_out, int out_size, void* d_ws, size_t ws_size,
                              hipStream_t stream) {
    const float* inp = (const float*)d_in[0];   // [8][4096][1792] f32
    const float* wgt = (const float*)d_in[1];   // [8][4096][1792] f32
    float* out = (float*)d_out;                 // [4096][4096] f32

    hipFuncSetAttribute(reinterpret_cast<const void*>(gemm_fused),
                        hipFuncAttributeMaxDynamicSharedMemorySize, 2 * LDSBUF);
    gemm_fused<<<256, 512, 2 * LDSBUF, stream>>>(inp, wgt, out);
}